// Round 1
// baseline (1492.186 us; speedup 1.0000x reference)
//
#include <hip/hip_runtime.h>

#define NN 50000
#define NE 800000
#define DD 256
#define NG 64
#define MPAD 50048  // 128 * 391

typedef __attribute__((ext_vector_type(8))) short bf16x8;
typedef __attribute__((ext_vector_type(4))) float f32x4;

__device__ __forceinline__ float bf2f(unsigned short u) {
  union { unsigned int i; float f; } v; v.i = ((unsigned int)u) << 16; return v.f;
}
__device__ __forceinline__ unsigned short f2bf(float f) {
  union { float f; unsigned int i; } v; v.f = f;
  unsigned int x = v.i;
  x += 0x7fffu + ((x >> 16) & 1u);  // RNE
  return (unsigned short)(x >> 16);
}

// ---------------- init / casts ----------------
__global__ void k_zero(unsigned int* __restrict__ p, int n) {
  int i = blockIdx.x * blockDim.x + threadIdx.x;
  int st = gridDim.x * blockDim.x;
  for (; i < n; i += st) p[i] = 0u;
}

// Wt[n][k] = bf16(W1[k][n])  (pre-transposed B for GEMM)
__global__ void k_castW(const float* __restrict__ W, unsigned short* __restrict__ Wt) {
  int i = blockIdx.x * blockDim.x + threadIdx.x;  // 65536
  int n = i >> 8, k = i & 255;
  Wt[i] = f2bf(W[k * 256 + n]);
}

// x (f32 [NN][256]) -> xb (bf16 [MPAD][256], pad rows zero)
__global__ void k_castX(const float* __restrict__ x, unsigned short* __restrict__ xb) {
  int i = blockIdx.x * blockDim.x + threadIdx.x;  // < MPAD*256/4
  int e = i * 4;
  int row = e >> 8;
  float4 v = make_float4(0.f, 0.f, 0.f, 0.f);
  if (row < NN) v = *(const float4*)(x + e);
  ushort4 u;
  u.x = f2bf(v.x); u.y = f2bf(v.y); u.z = f2bf(v.z); u.w = f2bf(v.w);
  *(ushort4*)(xb + e) = u;
}

// ---------------- GEMM: C[MPAD][256] = A[MPAD][256] @ B, with Bt[n][k] ----------------
// tile 128x64, BK=32, 4 waves (2x2), wave tile 64x32, mfma 16x16x32 bf16
__global__ __launch_bounds__(256) void k_gemm(const unsigned short* __restrict__ A,
                                              const unsigned short* __restrict__ Bt,
                                              unsigned short* __restrict__ C) {
  __shared__ unsigned short As[128][40];  // +8 pad: conflict-free ds_read_b128
  __shared__ unsigned short Bs[64][40];
  int tid = threadIdx.x;
  int lane = tid & 63;
  int wave = tid >> 6;
  int wm = wave >> 1, wn = wave & 1;
  int m0 = blockIdx.x * 128, n0 = blockIdx.y * 64;
  int l15 = lane & 15, l4 = lane >> 4;
  f32x4 acc[4][2] = {};

  for (int ks = 0; ks < 8; ++ks) {
    int k0 = ks * 32;
    {
      int c = tid, r = c >> 2, cc = c & 3;
      *(uint4*)(&As[r][cc * 8]) = *(const uint4*)(A + (size_t)(m0 + r) * 256 + k0 + cc * 8);
      c = tid + 256; r = c >> 2; cc = c & 3;
      *(uint4*)(&As[r][cc * 8]) = *(const uint4*)(A + (size_t)(m0 + r) * 256 + k0 + cc * 8);
      c = tid; r = c >> 2; cc = c & 3;
      *(uint4*)(&Bs[r][cc * 8]) = *(const uint4*)(Bt + (size_t)(n0 + r) * 256 + k0 + cc * 8);
    }
    __syncthreads();
    bf16x8 a[4], b[2];
#pragma unroll
    for (int fm = 0; fm < 4; ++fm)
      a[fm] = *(const bf16x8*)(&As[wm * 64 + fm * 16 + l15][l4 * 8]);
#pragma unroll
    for (int fn = 0; fn < 2; ++fn)
      b[fn] = *(const bf16x8*)(&Bs[wn * 32 + fn * 16 + l15][l4 * 8]);
#pragma unroll
    for (int fm = 0; fm < 4; ++fm)
#pragma unroll
      for (int fn = 0; fn < 2; ++fn)
        acc[fm][fn] = __builtin_amdgcn_mfma_f32_16x16x32_bf16(a[fm], b[fn], acc[fm][fn], 0, 0, 0);
    __syncthreads();
  }
  int r0 = l4 * 4;
#pragma unroll
  for (int fm = 0; fm < 4; ++fm)
#pragma unroll
    for (int fn = 0; fn < 2; ++fn) {
      int row = m0 + wm * 64 + fm * 16 + r0;
      int col = n0 + wn * 32 + fn * 16 + l15;
#pragma unroll
      for (int r = 0; r < 4; ++r)
        C[(size_t)(row + r) * 256 + col] = f2bf(acc[fm][fn][r]);
    }
}

// ---------------- graph prep ----------------
__global__ void k_hist(const int* __restrict__ dst, const int* __restrict__ batch,
                       int* __restrict__ deg, int* __restrict__ cnt) {
  int i = blockIdx.x * blockDim.x + threadIdx.x;
  int st = gridDim.x * blockDim.x;
  for (; i < NE + NN; i += st) {
    if (i < NE) atomicAdd(&deg[dst[i]], 1);
    else atomicAdd(&cnt[batch[i - NE]], 1);
  }
}

__global__ void k_dinv(const int* __restrict__ deg, float* __restrict__ dinv) {
  int i = blockIdx.x * blockDim.x + threadIdx.x;
  if (i < NN) dinv[i] = rsqrtf((float)deg[i] + 1.0f);  // +1 self-loop
}

#define SCAN_T 1024
__global__ __launch_bounds__(SCAN_T) void k_scan(const int* __restrict__ deg, int* __restrict__ rp) {
  __shared__ int s[SCAN_T];
  int t = threadIdx.x;
  const int chunk = (NN + SCAN_T - 1) / SCAN_T;
  int lo = t * chunk, hi = min(lo + chunk, NN);
  int sum = 0;
  for (int i = lo; i < hi; ++i) sum += deg[i];
  s[t] = sum;
  __syncthreads();
  for (int off = 1; off < SCAN_T; off <<= 1) {
    int v = (t >= off) ? s[t - off] : 0;
    __syncthreads();
    s[t] += v;
    __syncthreads();
  }
  int run = (t == 0) ? 0 : s[t - 1];
  for (int i = lo; i < hi; ++i) { rp[i] = run; run += deg[i]; }
  if (lo < NN && hi == NN) rp[NN] = run;
}

__global__ void k_starts(const int* __restrict__ cnt, int* __restrict__ starts) {
  if (threadIdx.x == 0) {
    int run = 0;
    for (int g = 0; g < NG; ++g) { starts[g] = run; run += cnt[g]; }
    starts[NG] = run;
  }
}

__global__ void k_fill(const int* __restrict__ src, const int* __restrict__ dst,
                       const int* __restrict__ rp, const float* __restrict__ dinv,
                       int* __restrict__ fill, int* __restrict__ csr_src,
                       float* __restrict__ csr_norm) {
  int i = blockIdx.x * blockDim.x + threadIdx.x;
  int st = gridDim.x * blockDim.x;
  for (; i < NE; i += st) {
    int s = src[i], d = dst[i];
    int pos = atomicAdd(&fill[d], 1);
    int idx = rp[d] + pos;
    csr_src[idx] = s;
    csr_norm[idx] = dinv[s] * dinv[d];
  }
}

// ---------------- aggregation 1: z = elu(A_norm @ h1 + b1), bf16 out ----------------
__global__ __launch_bounds__(256) void k_agg1(const unsigned short* __restrict__ h1,
                                              const int* __restrict__ csr_src,
                                              const float* __restrict__ csr_norm,
                                              const int* __restrict__ rp,
                                              const float* __restrict__ dinv,
                                              const float* __restrict__ b1,
                                              unsigned short* __restrict__ z) {
  __shared__ int s_src[256];
  __shared__ float s_nrm[256];
  int d = blockIdx.x, j = threadIdx.x;
  int es = rp[d], ee = rp[d + 1];
  float acc = 0.f;
  for (int base = es; base < ee; base += 256) {
    int cnt = min(256, ee - base);
    if (j < cnt) { s_src[j] = csr_src[base + j]; s_nrm[j] = csr_norm[base + j]; }
    __syncthreads();
    for (int e = 0; e < cnt; ++e)
      acc += s_nrm[e] * bf2f(h1[(size_t)s_src[e] * 256 + j]);
    __syncthreads();
  }
  float di = dinv[d];
  acc += di * di * bf2f(h1[(size_t)d * 256 + j]);
  acc += b1[j];
  float ez = acc > 0.f ? acc : expm1f(acc);
  z[(size_t)d * 256 + j] = f2bf(ez);
}

// ---------------- aggregation 2: pooled per-graph sum of norm*z[src] ----------------
__global__ __launch_bounds__(256) void k_agg2(const unsigned short* __restrict__ z,
                                              const int* __restrict__ csr_src,
                                              const float* __restrict__ csr_norm,
                                              const int* __restrict__ rp,
                                              const int* __restrict__ starts,
                                              const float* __restrict__ dinv,
                                              float* __restrict__ pool) {
  int g = blockIdx.x, ch = blockIdx.y, j = threadIdx.x;
  int CH = gridDim.y;
  int ns = starts[g], ne = starts[g + 1];
  int es = rp[ns], ee = rp[ne];
  float acc = 0.f;
  for (int i = es + ch; i < ee; i += CH)
    acc += csr_norm[i] * bf2f(z[(size_t)csr_src[i] * 256 + j]);
  for (int v = ns + ch; v < ne; v += CH) {
    float di = dinv[v];
    acc += di * di * bf2f(z[(size_t)v * 256 + j]);
  }
  atomicAdd(&pool[g * 256 + j], acc);
}

// ---------------- f = (pool/c) @ W2 + b2 ----------------
__global__ __launch_bounds__(256) void k_featF(const float* __restrict__ pool_s,
                                               const float* __restrict__ pool_n,
                                               const int* __restrict__ cnt_s,
                                               const int* __restrict__ cnt_n,
                                               const float* __restrict__ W2,
                                               const float* __restrict__ b2,
                                               float* __restrict__ fstate,
                                               float* __restrict__ fnext,
                                               float* __restrict__ out) {
  int g = blockIdx.x, which = blockIdx.y, j = threadIdx.x;
  const float* pool = which ? pool_n : pool_s;
  int c = which ? cnt_n[g] : cnt_s[g];
  __shared__ float v[256];
  float cc = fmaxf((float)c, 1.0f);
  v[j] = pool[g * 256 + j] / cc;
  __syncthreads();
  float acc = 0.f;
  for (int k = 0; k < 256; ++k) acc += v[k] * W2[k * 256 + j];
  float val = (c > 0) ? (acc + b2[j]) : 0.f;
  if (which) { fnext[g * 256 + j] = val; out[g * 256 + j] = val; }
  else fstate[g * 256 + j] = val;
}

// ---------------- heads: forward model + inverse model ----------------
__global__ __launch_bounds__(256) void k_head(const float* __restrict__ fstate,
                                              const float* __restrict__ fnext,
                                              const int* __restrict__ action,
                                              const float* __restrict__ Wf, const float* __restrict__ bfv,
                                              const float* __restrict__ Wi1, const float* __restrict__ bi1,
                                              const float* __restrict__ Wi2, const float* __restrict__ bi2,
                                              const float* __restrict__ Wi3, const float* __restrict__ bi3,
                                              float* __restrict__ out) {
  int g = blockIdx.x, j = threadIdx.x;
  __shared__ float fs[256], fn_[256], z1[128], z2[128];
  fs[j] = fstate[g * 256 + j];
  fn_[j] = fnext[g * 256 + j];
  __syncthreads();
  // next_state_hat = Wf[action] + fs @ Wf[16:,:] + bf
  int a = action[g];
  float acc = bfv[j] + Wf[a * 256 + j];
  for (int k = 0; k < 256; ++k) acc += fs[k] * Wf[(16 + k) * 256 + j];
  out[16384 + g * 256 + j] = acc;
  // inverse model
  if (j < 128) {
    float t = bi1[j];
    for (int k = 0; k < 256; ++k)
      t += fs[k] * Wi1[k * 128 + j] + fn_[k] * Wi1[(256 + k) * 128 + j];
    z1[j] = fmaxf(t, 0.f);
  }
  __syncthreads();
  if (j < 128) {
    float t = bi2[j];
    for (int k = 0; k < 128; ++k) t += z1[k] * Wi2[k * 128 + j];
    z2[j] = fmaxf(t, 0.f);
  }
  __syncthreads();
  if (j < 16) {
    float t = bi3[j];
    for (int k = 0; k < 128; ++k) t += z2[k] * Wi3[k * 16 + j];
    out[32768 + g * 16 + j] = t;
  }
}

// ---------------- workspace layout ----------------
static constexpr size_t AL(size_t x) { return (x + 255) & ~(size_t)255; }
static constexpr size_t O_XB   = 0;
static constexpr size_t O_H1   = O_XB + AL((size_t)MPAD * DD * 2);
static constexpr size_t O_Z    = O_H1 + AL((size_t)MPAD * DD * 2);
static constexpr size_t O_CSRS = O_Z + AL((size_t)NN * DD * 2);
static constexpr size_t O_CSRN = O_CSRS + AL((size_t)NE * 4);
static constexpr size_t O_RP   = O_CSRN + AL((size_t)NE * 4);
static constexpr size_t O_DINV = O_RP + AL((size_t)(NN + 1) * 4);
static constexpr size_t O_ST   = O_DINV + AL((size_t)NN * 4);
static constexpr size_t O_WT   = O_ST + AL(65 * 4);
static constexpr size_t O_FS   = O_WT + AL((size_t)DD * DD * 2);
static constexpr size_t O_FN   = O_FS + AL((size_t)NG * DD * 4);
static constexpr size_t O_ZERO = O_FN + AL((size_t)NG * DD * 4);
static constexpr size_t O_DEGS = O_ZERO;
static constexpr size_t O_DEGN = O_DEGS + AL((size_t)NN * 4);
static constexpr size_t O_FILS = O_DEGN + AL((size_t)NN * 4);
static constexpr size_t O_FILN = O_FILS + AL((size_t)NN * 4);
static constexpr size_t O_CNTS = O_FILN + AL((size_t)NN * 4);
static constexpr size_t O_CNTN = O_CNTS + AL(NG * 4);
static constexpr size_t O_PS   = O_CNTN + AL(NG * 4);
static constexpr size_t O_PN   = O_PS + AL((size_t)NG * DD * 4);
static constexpr size_t O_END  = O_PN + AL((size_t)NG * DD * 4);

extern "C" void kernel_launch(void* const* d_in, const int* in_sizes, int n_in,
                              void* d_out, int out_size, void* d_ws, size_t ws_size,
                              hipStream_t stream) {
  const float* x_s     = (const float*)d_in[0];
  const int*   ei_s    = (const int*)d_in[1];
  const int*   batch_s = (const int*)d_in[2];
  const float* x_n     = (const float*)d_in[3];
  const int*   ei_n    = (const int*)d_in[4];
  const int*   batch_n = (const int*)d_in[5];
  const int*   action  = (const int*)d_in[6];
  const float* W1      = (const float*)d_in[7];
  const float* b1      = (const float*)d_in[8];
  const float* W2      = (const float*)d_in[9];
  const float* b2      = (const float*)d_in[10];
  const float* Wf      = (const float*)d_in[11];
  const float* bfv     = (const float*)d_in[12];
  const float* Wi1     = (const float*)d_in[13];
  const float* bi1     = (const float*)d_in[14];
  const float* Wi2     = (const float*)d_in[15];
  const float* bi2     = (const float*)d_in[16];
  const float* Wi3     = (const float*)d_in[17];
  const float* bi3     = (const float*)d_in[18];
  float* out = (float*)d_out;
  char* ws = (char*)d_ws;
  if (ws_size < O_END) return;  // workspace too small -> fail visibly

  unsigned short* xb   = (unsigned short*)(ws + O_XB);
  unsigned short* h1   = (unsigned short*)(ws + O_H1);
  unsigned short* zb   = (unsigned short*)(ws + O_Z);
  int*   csr_src = (int*)(ws + O_CSRS);
  float* csr_nrm = (float*)(ws + O_CSRN);
  int*   rp      = (int*)(ws + O_RP);
  float* dinv    = (float*)(ws + O_DINV);
  int*   starts  = (int*)(ws + O_ST);
  unsigned short* Wt = (unsigned short*)(ws + O_WT);
  float* fstate  = (float*)(ws + O_FS);
  float* fnext   = (float*)(ws + O_FN);
  int*   deg[2]  = { (int*)(ws + O_DEGS), (int*)(ws + O_DEGN) };
  int*   fil[2]  = { (int*)(ws + O_FILS), (int*)(ws + O_FILN) };
  int*   cnt[2]  = { (int*)(ws + O_CNTS), (int*)(ws + O_CNTN) };
  float* pool[2] = { (float*)(ws + O_PS), (float*)(ws + O_PN) };

  // zero the accumulated region (deg/fill/cnt/pool, both graphs)
  int zero_words = (int)((O_END - O_ZERO) / 4);
  k_zero<<<(zero_words + 255) / 256, 256, 0, stream>>>((unsigned int*)(ws + O_ZERO), zero_words);
  k_castW<<<(DD * DD) / 256, 256, 0, stream>>>(W1, Wt);

  const float* xs[2]  = { x_s, x_n };
  const int*   eis[2] = { ei_s, ei_n };
  const int*   bts[2] = { batch_s, batch_n };

  for (int gidx = 0; gidx < 2; ++gidx) {
    const float* x = xs[gidx];
    const int* src = eis[gidx];
    const int* dst = eis[gidx] + NE;
    const int* batch = bts[gidx];
    k_castX<<<(MPAD * DD / 4) / 256, 256, 0, stream>>>(x, xb);
    k_gemm<<<dim3(MPAD / 128, DD / 64), 256, 0, stream>>>(xb, Wt, h1);
    k_hist<<<(NE + NN + 255) / 256, 256, 0, stream>>>(dst, batch, deg[gidx], cnt[gidx]);
    k_dinv<<<(NN + 255) / 256, 256, 0, stream>>>(deg[gidx], dinv);
    k_scan<<<1, SCAN_T, 0, stream>>>(deg[gidx], rp);
    k_starts<<<1, 64, 0, stream>>>(cnt[gidx], starts);
    k_fill<<<(NE + 255) / 256, 256, 0, stream>>>(src, dst, rp, dinv, fil[gidx], csr_src, csr_nrm);
    k_agg1<<<NN, 256, 0, stream>>>(h1, csr_src, csr_nrm, rp, dinv, b1, zb);
    k_agg2<<<dim3(NG, 32), 256, 0, stream>>>(zb, csr_src, csr_nrm, rp, starts, dinv, pool[gidx]);
  }

  k_featF<<<dim3(NG, 2), 256, 0, stream>>>(pool[0], pool[1], cnt[0], cnt[1], W2, b2,
                                           fstate, fnext, out);
  k_head<<<NG, 256, 0, stream>>>(fstate, fnext, action, Wf, bfv,
                                 Wi1, bi1, Wi2, bi2, Wi3, bi3, out);
}

// Round 2
// 1106.170 us; speedup vs baseline: 1.3490x; 1.3490x over previous
//
#include <hip/hip_runtime.h>

#define NN 50000
#define NE 800000
#define DD 256
#define NG 64
#define MPAD 50048  // 128 * 391

// counting-sort parameters
#define HC 32          // edge chunks (NE/HC = 25000, < 65536 so u16 bins never overflow)
#define EPC (NE / HC)  // 25000
#define HBINS 32768    // bins per part in histogram pass (u16-packed -> 64 KB LDS)
#define FBINS 16384    // bins per part in fill pass (u32 counters -> 64 KB LDS)

typedef __attribute__((ext_vector_type(8))) short bf16x8;
typedef __attribute__((ext_vector_type(4))) float f32x4;

__device__ __forceinline__ float bf2f(unsigned short u) {
  union { unsigned int i; float f; } v; v.i = ((unsigned int)u) << 16; return v.f;
}
__device__ __forceinline__ unsigned short f2bf(float f) {
  union { float f; unsigned int i; } v; v.f = f;
  unsigned int x = v.i;
  x += 0x7fffu + ((x >> 16) & 1u);  // RNE
  return (unsigned short)(x >> 16);
}

// ---------------- init / casts ----------------
__global__ void k_zero(unsigned int* __restrict__ p, int n) {
  int i = blockIdx.x * blockDim.x + threadIdx.x;
  int st = gridDim.x * blockDim.x;
  for (; i < n; i += st) p[i] = 0u;
}

// Wt[n][k] = bf16(W1[k][n])  (pre-transposed B for GEMM)
__global__ void k_castW(const float* __restrict__ W, unsigned short* __restrict__ Wt) {
  int i = blockIdx.x * blockDim.x + threadIdx.x;  // 65536
  int n = i >> 8, k = i & 255;
  Wt[i] = f2bf(W[k * 256 + n]);
}

// x (f32 [NN][256]) -> xb (bf16 [MPAD][256], pad rows zero)
__global__ void k_castX(const float* __restrict__ x, unsigned short* __restrict__ xb) {
  int i = blockIdx.x * blockDim.x + threadIdx.x;  // < MPAD*256/4
  int e = i * 4;
  int row = e >> 8;
  float4 v = make_float4(0.f, 0.f, 0.f, 0.f);
  if (row < NN) v = *(const float4*)(x + e);
  ushort4 u;
  u.x = f2bf(v.x); u.y = f2bf(v.y); u.z = f2bf(v.z); u.w = f2bf(v.w);
  *(ushort4*)(xb + e) = u;
}

// ---------------- GEMM: C[MPAD][256] = A[MPAD][256] @ B, with Bt[n][k] ----------------
__global__ __launch_bounds__(256) void k_gemm(const unsigned short* __restrict__ A,
                                              const unsigned short* __restrict__ Bt,
                                              unsigned short* __restrict__ C) {
  __shared__ unsigned short As[128][40];
  __shared__ unsigned short Bs[64][40];
  int tid = threadIdx.x;
  int lane = tid & 63;
  int wave = tid >> 6;
  int wm = wave >> 1, wn = wave & 1;
  int m0 = blockIdx.x * 128, n0 = blockIdx.y * 64;
  int l15 = lane & 15, l4 = lane >> 4;
  f32x4 acc[4][2] = {};

  for (int ks = 0; ks < 8; ++ks) {
    int k0 = ks * 32;
    {
      int c = tid, r = c >> 2, cc = c & 3;
      *(uint4*)(&As[r][cc * 8]) = *(const uint4*)(A + (size_t)(m0 + r) * 256 + k0 + cc * 8);
      c = tid + 256; r = c >> 2; cc = c & 3;
      *(uint4*)(&As[r][cc * 8]) = *(const uint4*)(A + (size_t)(m0 + r) * 256 + k0 + cc * 8);
      c = tid; r = c >> 2; cc = c & 3;
      *(uint4*)(&Bs[r][cc * 8]) = *(const uint4*)(Bt + (size_t)(n0 + r) * 256 + k0 + cc * 8);
    }
    __syncthreads();
    bf16x8 a[4], b[2];
#pragma unroll
    for (int fm = 0; fm < 4; ++fm)
      a[fm] = *(const bf16x8*)(&As[wm * 64 + fm * 16 + l15][l4 * 8]);
#pragma unroll
    for (int fn = 0; fn < 2; ++fn)
      b[fn] = *(const bf16x8*)(&Bs[wn * 32 + fn * 16 + l15][l4 * 8]);
#pragma unroll
    for (int fm = 0; fm < 4; ++fm)
#pragma unroll
      for (int fn = 0; fn < 2; ++fn)
        acc[fm][fn] = __builtin_amdgcn_mfma_f32_16x16x32_bf16(a[fm], b[fn], acc[fm][fn], 0, 0, 0);
    __syncthreads();
  }
  int r0 = l4 * 4;
#pragma unroll
  for (int fm = 0; fm < 4; ++fm)
#pragma unroll
    for (int fn = 0; fn < 2; ++fn) {
      int row = m0 + wm * 64 + fm * 16 + r0;
      int col = n0 + wn * 32 + fn * 16 + l15;
#pragma unroll
      for (int r = 0; r < 4; ++r)
        C[(size_t)(row + r) * 256 + col] = f2bf(acc[fm][fn][r]);
    }
}

// ---------------- graph prep: LDS-privatized counting sort by dst ----------------
// pass A: per-(chunk,part) u16-packed LDS histogram -> partial[c][bin] (u16)
__global__ __launch_bounds__(256) void k_hist2(const int* __restrict__ dst,
                                               unsigned int* __restrict__ partial) {
  __shared__ unsigned int lh[HBINS / 2];  // 64 KB: u16-packed bins
  int tid = threadIdx.x;
  int c = blockIdx.x, p = blockIdx.y;
  for (int w = tid; w < HBINS / 2; w += 256) lh[w] = 0u;
  __syncthreads();
  int lo = c * EPC, hi = lo + EPC;
  int b0 = p * HBINS;
  for (int i = lo + tid; i < hi; i += 256) {
    int rel = dst[i] - b0;
    if ((unsigned)rel < (unsigned)HBINS)
      atomicAdd(&lh[rel >> 1], 1u << ((rel & 1) * 16));
  }
  __syncthreads();
  // partial row = NN/2 u32 words (NN even)
  int wbase = p * (HBINS / 2);
  for (int w = tid; w < HBINS / 2; w += 256) {
    int gw = wbase + w;
    if (gw < NN / 2) partial[(size_t)c * (NN / 2) + gw] = lh[w];
  }
}

// reduce partials -> deg
__global__ void k_reduce(const unsigned int* __restrict__ partial, int* __restrict__ deg) {
  int w = blockIdx.x * blockDim.x + threadIdx.x;
  if (w >= NN / 2) return;
  unsigned int sl = 0, sh = 0;
#pragma unroll
  for (int c = 0; c < HC; ++c) {
    unsigned int v = partial[(size_t)c * (NN / 2) + w];
    sl += v & 0xffffu;
    sh += v >> 16;
  }
  *(int2*)(deg + 2 * w) = make_int2((int)sl, (int)sh);
}

__global__ void k_dinv(const int* __restrict__ deg, float* __restrict__ dinv) {
  int i = blockIdx.x * blockDim.x + threadIdx.x;
  if (i < NN) dinv[i] = rsqrtf((float)deg[i] + 1.0f);  // +1 self-loop
}

#define SCAN_T 1024
__global__ __launch_bounds__(SCAN_T) void k_scan(const int* __restrict__ deg, int* __restrict__ rp) {
  __shared__ int s[SCAN_T];
  int t = threadIdx.x;
  const int chunk = (NN + SCAN_T - 1) / SCAN_T;
  int lo = t * chunk, hi = min(lo + chunk, NN);
  int sum = 0;
  for (int i = lo; i < hi; ++i) sum += deg[i];
  s[t] = sum;
  __syncthreads();
  for (int off = 1; off < SCAN_T; off <<= 1) {
    int v = (t >= off) ? s[t - off] : 0;
    __syncthreads();
    s[t] += v;
    __syncthreads();
  }
  int run = (t == 0) ? 0 : s[t - 1];
  for (int i = lo; i < hi; ++i) { rp[i] = run; run += deg[i]; }
  if (lo < NN && hi == NN) rp[NN] = run;
}

// per-(chunk,bin) placement base: base[c][b] = rp[b] + sum_{c'<c} partial[c'][b]
__global__ void k_base(const unsigned short* __restrict__ partial16,
                       const int* __restrict__ rp, int* __restrict__ base) {
  int b = blockIdx.x * blockDim.x + threadIdx.x;
  if (b >= NN) return;
  int run = rp[b];
#pragma unroll
  for (int c = 0; c < HC; ++c) {
    base[(size_t)c * NN + b] = run;
    run += (int)partial16[(size_t)c * NN + b];
  }
}

// graph boundaries from sorted batch -> starts[0..NG]
__global__ void k_bounds(const int* __restrict__ batch, int* __restrict__ starts) {
  int i = blockIdx.x * blockDim.x + threadIdx.x;
  if (i > NN) return;
  if (i == 0) {
    int b0 = batch[0];
    for (int g = 0; g <= b0; ++g) starts[g] = 0;
  } else if (i == NN) {
    int bl = batch[NN - 1];
    for (int g = bl + 1; g <= NG; ++g) starts[g] = NN;
  } else {
    int a = batch[i - 1], b = batch[i];
    for (int g = a + 1; g <= b; ++g) starts[g] = i;
  }
}

// pass C: fill CSR using LDS position counters (no global atomics)
__global__ __launch_bounds__(256) void k_fill2(const int* __restrict__ src,
                                               const int* __restrict__ dst,
                                               const int* __restrict__ base,
                                               const float* __restrict__ dinv,
                                               int* __restrict__ csr_src,
                                               float* __restrict__ csr_norm) {
  __shared__ unsigned int pos[FBINS];  // 64 KB
  int tid = threadIdx.x;
  int c = blockIdx.x, p = blockIdx.y;
  int b0 = p * FBINS;
  for (int w = tid; w < FBINS; w += 256) {
    int gb = b0 + w;
    pos[w] = (gb < NN) ? (unsigned int)base[(size_t)c * NN + gb] : 0u;
  }
  __syncthreads();
  int lo = c * EPC, hi = lo + EPC;
  for (int i = lo + tid; i < hi; i += 256) {
    int d = dst[i];
    int s = src[i];
    int rel = d - b0;
    if ((unsigned)rel < (unsigned)FBINS) {
      int idx = (int)atomicAdd(&pos[rel], 1u);
      csr_src[idx] = s;
      csr_norm[idx] = dinv[s] * dinv[d];
    }
  }
}

// ---------------- aggregation 1: z = elu(A_norm @ h1 + b1), bf16 out ----------------
__global__ __launch_bounds__(256) void k_agg1(const unsigned short* __restrict__ h1,
                                              const int* __restrict__ csr_src,
                                              const float* __restrict__ csr_norm,
                                              const int* __restrict__ rp,
                                              const float* __restrict__ dinv,
                                              const float* __restrict__ b1,
                                              unsigned short* __restrict__ z) {
  __shared__ int s_src[256];
  __shared__ float s_nrm[256];
  int d = blockIdx.x, j = threadIdx.x;
  int es = rp[d], ee = rp[d + 1];
  float acc = 0.f;
  for (int base = es; base < ee; base += 256) {
    int cnt = min(256, ee - base);
    if (j < cnt) { s_src[j] = csr_src[base + j]; s_nrm[j] = csr_norm[base + j]; }
    __syncthreads();
    for (int e = 0; e < cnt; ++e)
      acc += s_nrm[e] * bf2f(h1[(size_t)s_src[e] * 256 + j]);
    __syncthreads();
  }
  float di = dinv[d];
  acc += di * di * bf2f(h1[(size_t)d * 256 + j]);
  acc += b1[j];
  float ez = acc > 0.f ? acc : expm1f(acc);
  z[(size_t)d * 256 + j] = f2bf(ez);
}

// ---------------- aggregation 2: pooled per-graph sum of norm*z[src] ----------------
__global__ __launch_bounds__(256) void k_agg2(const unsigned short* __restrict__ z,
                                              const int* __restrict__ csr_src,
                                              const float* __restrict__ csr_norm,
                                              const int* __restrict__ rp,
                                              const int* __restrict__ starts,
                                              const float* __restrict__ dinv,
                                              float* __restrict__ pool) {
  int g = blockIdx.x, ch = blockIdx.y, j = threadIdx.x;
  int CH = gridDim.y;
  int ns = starts[g], ne = starts[g + 1];
  int es = rp[ns], ee = rp[ne];
  float acc = 0.f;
  for (int i = es + ch; i < ee; i += CH)
    acc += csr_norm[i] * bf2f(z[(size_t)csr_src[i] * 256 + j]);
  for (int v = ns + ch; v < ne; v += CH) {
    float di = dinv[v];
    acc += di * di * bf2f(z[(size_t)v * 256 + j]);
  }
  atomicAdd(&pool[g * 256 + j], acc);
}

// ---------------- f = (pool/c) @ W2 + b2 ----------------
__global__ __launch_bounds__(256) void k_featF(const float* __restrict__ pool_s,
                                               const float* __restrict__ pool_n,
                                               const int* __restrict__ st_s,
                                               const int* __restrict__ st_n,
                                               const float* __restrict__ W2,
                                               const float* __restrict__ b2,
                                               float* __restrict__ fstate,
                                               float* __restrict__ fnext,
                                               float* __restrict__ out) {
  int g = blockIdx.x, which = blockIdx.y, j = threadIdx.x;
  const float* pool = which ? pool_n : pool_s;
  const int* st = which ? st_n : st_s;
  int c = st[g + 1] - st[g];
  __shared__ float v[256];
  float cc = fmaxf((float)c, 1.0f);
  v[j] = pool[g * 256 + j] / cc;
  __syncthreads();
  float acc = 0.f;
  for (int k = 0; k < 256; ++k) acc += v[k] * W2[k * 256 + j];
  float val = (c > 0) ? (acc + b2[j]) : 0.f;
  if (which) { fnext[g * 256 + j] = val; out[g * 256 + j] = val; }
  else fstate[g * 256 + j] = val;
}

// ---------------- heads ----------------
__global__ __launch_bounds__(256) void k_head(const float* __restrict__ fstate,
                                              const float* __restrict__ fnext,
                                              const int* __restrict__ action,
                                              const float* __restrict__ Wf, const float* __restrict__ bfv,
                                              const float* __restrict__ Wi1, const float* __restrict__ bi1,
                                              const float* __restrict__ Wi2, const float* __restrict__ bi2,
                                              const float* __restrict__ Wi3, const float* __restrict__ bi3,
                                              float* __restrict__ out) {
  int g = blockIdx.x, j = threadIdx.x;
  __shared__ float fs[256], fn_[256], z1[128], z2[128];
  fs[j] = fstate[g * 256 + j];
  fn_[j] = fnext[g * 256 + j];
  __syncthreads();
  int a = action[g];
  float acc = bfv[j] + Wf[a * 256 + j];
  for (int k = 0; k < 256; ++k) acc += fs[k] * Wf[(16 + k) * 256 + j];
  out[16384 + g * 256 + j] = acc;
  if (j < 128) {
    float t = bi1[j];
    for (int k = 0; k < 256; ++k)
      t += fs[k] * Wi1[k * 128 + j] + fn_[k] * Wi1[(256 + k) * 128 + j];
    z1[j] = fmaxf(t, 0.f);
  }
  __syncthreads();
  if (j < 128) {
    float t = bi2[j];
    for (int k = 0; k < 128; ++k) t += z1[k] * Wi2[k * 128 + j];
    z2[j] = fmaxf(t, 0.f);
  }
  __syncthreads();
  if (j < 16) {
    float t = bi3[j];
    for (int k = 0; k < 128; ++k) t += z2[k] * Wi3[k * 16 + j];
    out[32768 + g * 16 + j] = t;
  }
}

// ---------------- workspace layout ----------------
static constexpr size_t AL(size_t x) { return (x + 255) & ~(size_t)255; }
static constexpr size_t O_XB   = 0;
static constexpr size_t O_H1   = O_XB + AL((size_t)MPAD * DD * 2);      // 25.6 MB region
static constexpr size_t O_Z    = O_H1 + AL((size_t)MPAD * DD * 2);
static constexpr size_t O_CSRS = O_Z + AL((size_t)NN * DD * 2);
static constexpr size_t O_CSRN = O_CSRS + AL((size_t)NE * 4);
static constexpr size_t O_RP   = O_CSRN + AL((size_t)NE * 4);
static constexpr size_t O_DINV = O_RP + AL((size_t)(NN + 1) * 4);
static constexpr size_t O_DEG  = O_DINV + AL((size_t)NN * 4);
static constexpr size_t O_ST0  = O_DEG + AL((size_t)NN * 4);
static constexpr size_t O_ST1  = O_ST0 + AL((NG + 1) * 4);
static constexpr size_t O_WT   = O_ST1 + AL((NG + 1) * 4);
static constexpr size_t O_FS   = O_WT + AL((size_t)DD * DD * 2);
static constexpr size_t O_FN   = O_FS + AL((size_t)NG * DD * 4);
static constexpr size_t O_ZERO = O_FN + AL((size_t)NG * DD * 4);
static constexpr size_t O_PS   = O_ZERO;
static constexpr size_t O_PN   = O_PS + AL((size_t)NG * DD * 4);
static constexpr size_t O_END  = O_PN + AL((size_t)NG * DD * 4);
// scratch aliased inside the h1 region (used only before k_gemm writes h1):
static constexpr size_t O_PART = O_H1;                         // HC * NN/2 u32 = 3.2 MB
static constexpr size_t O_BASE = O_H1 + AL((size_t)HC * (NN / 2) * 4);  // HC * NN u32 = 6.4 MB

extern "C" void kernel_launch(void* const* d_in, const int* in_sizes, int n_in,
                              void* d_out, int out_size, void* d_ws, size_t ws_size,
                              hipStream_t stream) {
  const float* x_s     = (const float*)d_in[0];
  const int*   ei_s    = (const int*)d_in[1];
  const int*   batch_s = (const int*)d_in[2];
  const float* x_n     = (const float*)d_in[3];
  const int*   ei_n    = (const int*)d_in[4];
  const int*   batch_n = (const int*)d_in[5];
  const int*   action  = (const int*)d_in[6];
  const float* W1      = (const float*)d_in[7];
  const float* b1      = (const float*)d_in[8];
  const float* W2      = (const float*)d_in[9];
  const float* b2      = (const float*)d_in[10];
  const float* Wf      = (const float*)d_in[11];
  const float* bfv     = (const float*)d_in[12];
  const float* Wi1     = (const float*)d_in[13];
  const float* bi1     = (const float*)d_in[14];
  const float* Wi2     = (const float*)d_in[15];
  const float* bi2     = (const float*)d_in[16];
  const float* Wi3     = (const float*)d_in[17];
  const float* bi3     = (const float*)d_in[18];
  float* out = (float*)d_out;
  char* ws = (char*)d_ws;
  if (ws_size < O_END) return;

  unsigned short* xb   = (unsigned short*)(ws + O_XB);
  unsigned short* h1   = (unsigned short*)(ws + O_H1);
  unsigned short* zb   = (unsigned short*)(ws + O_Z);
  int*   csr_src = (int*)(ws + O_CSRS);
  float* csr_nrm = (float*)(ws + O_CSRN);
  int*   rp      = (int*)(ws + O_RP);
  float* dinv    = (float*)(ws + O_DINV);
  int*   deg     = (int*)(ws + O_DEG);
  unsigned short* Wt = (unsigned short*)(ws + O_WT);
  float* fstate  = (float*)(ws + O_FS);
  float* fnext   = (float*)(ws + O_FN);
  int*   starts[2] = { (int*)(ws + O_ST0), (int*)(ws + O_ST1) };
  float* pool[2]   = { (float*)(ws + O_PS), (float*)(ws + O_PN) };
  unsigned int* partial = (unsigned int*)(ws + O_PART);
  int*          basebuf = (int*)(ws + O_BASE);

  int zero_words = (int)((O_END - O_ZERO) / 4);
  k_zero<<<(zero_words + 255) / 256, 256, 0, stream>>>((unsigned int*)(ws + O_ZERO), zero_words);
  k_castW<<<(DD * DD) / 256, 256, 0, stream>>>(W1, Wt);

  const float* xs[2]  = { x_s, x_n };
  const int*   eis[2] = { ei_s, ei_n };
  const int*   bts[2] = { batch_s, batch_n };

  for (int gidx = 0; gidx < 2; ++gidx) {
    const float* x = xs[gidx];
    const int* src = eis[gidx];
    const int* dst = eis[gidx] + NE;
    const int* batch = bts[gidx];
    k_castX<<<(MPAD * DD / 4) / 256, 256, 0, stream>>>(x, xb);
    // --- graph prep (no global atomics) --- uses h1 region as scratch
    k_hist2<<<dim3(HC, 2), 256, 0, stream>>>(dst, partial);
    k_reduce<<<(NN / 2 + 255) / 256, 256, 0, stream>>>(partial, deg);
    k_dinv<<<(NN + 255) / 256, 256, 0, stream>>>(deg, dinv);
    k_scan<<<1, SCAN_T, 0, stream>>>(deg, rp);
    k_bounds<<<(NN + 1 + 255) / 256, 256, 0, stream>>>(batch, starts[gidx]);
    k_base<<<(NN + 255) / 256, 256, 0, stream>>>((const unsigned short*)partial, rp, basebuf);
    k_fill2<<<dim3(HC, (NN + FBINS - 1) / FBINS), 256, 0, stream>>>(src, dst, basebuf, dinv,
                                                                    csr_src, csr_nrm);
    // --- dense + aggregate --- (gemm overwrites the scratch region)
    k_gemm<<<dim3(MPAD / 128, DD / 64), 256, 0, stream>>>(xb, Wt, h1);
    k_agg1<<<NN, 256, 0, stream>>>(h1, csr_src, csr_nrm, rp, dinv, b1, zb);
    k_agg2<<<dim3(NG, 32), 256, 0, stream>>>(zb, csr_src, csr_nrm, rp, starts[gidx], dinv, pool[gidx]);
  }

  k_featF<<<dim3(NG, 2), 256, 0, stream>>>(pool[0], pool[1], starts[0], starts[1], W2, b2,
                                           fstate, fnext, out);
  k_head<<<NG, 256, 0, stream>>>(fstate, fnext, action, Wf, bfv,
                                 Wi1, bi1, Wi2, bi2, Wi3, bi3, out);
}